// Round 19
// baseline (66.827 us; speedup 1.0000x reference)
//
#include <hip/hip_runtime.h>

#define B_ 8
#define C_ 128
#define L_ 2048
#define NE (B_ * L_ * C_)

typedef __attribute__((ext_vector_type(8))) short s8v;
typedef __attribute__((ext_vector_type(4))) short s4v;
typedef __attribute__((ext_vector_type(4))) float f4v;
typedef __attribute__((ext_vector_type(8))) float f8v;

// 1/sqrt(128) * log2(e)  (folded into Wq/bq so attn uses exp2 directly)
#define QSCALE 0.1275174106f
// 8 * log2(e)
#define ESHIFT 11.5415603272f

static __device__ inline short f2bf(float f) {
    union { float f; unsigned u; } v; v.f = f;
    unsigned r = v.u + 0x7FFFu + ((v.u >> 16) & 1u);
    return (short)(r >> 16);
}
static __device__ inline float bf2f(short s) {
    union { unsigned u; float f; } v; v.u = ((unsigned)(unsigned short)s) << 16;
    return v.f;
}
static __device__ inline unsigned cvt_pk_bf16(float lo, float hi) {
    unsigned r;
    asm("v_cvt_pk_bf16_f32 %0, %1, %2" : "=v"(r) : "v"(lo), "v"(hi));
    return r;
}
static __device__ inline void gload16(const void* g, void* l) {
    __builtin_amdgcn_global_load_lds(
        (const __attribute__((address_space(1))) unsigned int*)g,
        (__attribute__((address_space(3))) unsigned int*)l, 16, 0, 0);
}

#define WAIT_VM0 asm volatile("s_waitcnt vmcnt(0)" ::: "memory")

// ---------------------------------------------------------------------------
// prep: bf16 weights (Wq pre-scaled by QSCALE), scaled bq. grid 16x256.
// ---------------------------------------------------------------------------
__global__ __launch_bounds__(256) void prep(
    const float* __restrict__ Wq, const float* __restrict__ Wk,
    const float* __restrict__ Wv, const float* __restrict__ Wo,
    const float* __restrict__ bq, short* __restrict__ Wb, float* __restrict__ bqs)
{
    const int i = (blockIdx.x * 256 + threadIdx.x) * 4;
    const float* src[4] = { Wq, Wk, Wv, Wo };
#pragma unroll
    for (int m = 0; m < 4; ++m) {
        f4v v = *(const f4v*)(src[m] + i);
        const float mul = (m == 0) ? QSCALE : 1.f;
        union { s4v s; unsigned u[2]; } o;
        o.u[0] = cvt_pk_bf16(v[0] * mul, v[1] * mul);
        o.u[1] = cvt_pk_bf16(v[2] * mul, v[3] * mul);
        *(s4v*)(Wb + m * 16384 + i) = o.s;
    }
    if (blockIdx.x == 0 && threadIdx.x < C_) bqs[threadIdx.x] = bq[threadIdx.x] * QSCALE;
}

// ---------------------------------------------------------------------------
// Kernel A: h = relu(x); Q,K -> [B][L][C] bf16 ; V -> [B][C][L] bf16
// grid 1024 = b(8) x 128 l-tiles of 16 rows; waves own 6 (mat,nt) tiles each
// ---------------------------------------------------------------------------
__global__ __launch_bounds__(256) void qkv_proj(
    const float* __restrict__ x, const short* __restrict__ Wb,
    const float* __restrict__ bqs, const float* __restrict__ bk,
    const float* __restrict__ bv,
    short* __restrict__ Qb, short* __restrict__ Kb, short* __restrict__ Vt)
{
    __shared__ short ht[16][136];
    const int b  = blockIdx.x >> 7;
    const int l0 = (blockIdx.x & 127) * 16;
    const int tid = threadIdx.x;

    {
        const int c = tid >> 1, lh = (tid & 1) * 8;
        f8v v = *(const f8v*)(x + ((size_t)b * C_ + c) * L_ + l0 + lh);
#pragma unroll
        for (int j = 0; j < 8; ++j) ht[lh + j][c] = f2bf(fmaxf(v[j], 0.f));
    }
    __syncthreads();

    const int lane = tid & 63, w = tid >> 6;
    const int lr = lane & 15, lg = lane >> 4;

    s8v hf[4];
#pragma unroll
    for (int kk = 0; kk < 4; ++kk)
        hf[kk] = *(const s8v*)&ht[lr][kk * 32 + lg * 8];

#pragma unroll
    for (int i = 0; i < 6; ++i) {
        const int idx = w * 6 + i;
        const int mat = idx >> 3, nt = idx & 7;
        const short* W = Wb + mat * 16384;
        f4v acc = {0.f, 0.f, 0.f, 0.f};
#pragma unroll
        for (int kk = 0; kk < 4; ++kk) {
            s8v wfr = *(const s8v*)(W + (size_t)(nt * 16 + lr) * C_ + kk * 32 + lg * 8);
            acc = __builtin_amdgcn_mfma_f32_16x16x32_bf16(hf[kk], wfr, acc, 0, 0, 0);
        }
        const int o = nt * 16 + lr;
        const float bsc = (mat == 0 ? bqs : (mat == 1 ? bk : bv))[o];
        if (mat == 0) {
#pragma unroll
            for (int r = 0; r < 4; ++r)
                Qb[((size_t)b * L_ + l0 + 4 * lg + r) * C_ + o] = f2bf(acc[r] + bsc);
        } else if (mat == 1) {
#pragma unroll
            for (int r = 0; r < 4; ++r)
                Kb[((size_t)b * L_ + l0 + 4 * lg + r) * C_ + o] = f2bf(acc[r] + bsc);
        } else {
            union { s4v s; unsigned u[2]; } pk;
            pk.u[0] = cvt_pk_bf16(acc[0] + bsc, acc[1] + bsc);
            pk.u[1] = cvt_pk_bf16(acc[2] + bsc, acc[3] + bsc);
            *(s4v*)(Vt + ((size_t)b * C_ + o) * L_ + l0 + 4 * lg) = pk.s;
        }
    }
}

// ---------------------------------------------------------------------------
// Kernel B: flash attention, fixed-shift exp2 softmax, 4-way split-K.
// QBLK=128: each wave owns 32 q-rows (2 rowgroups), all 4 waves share each
// KV tile (KVB=32, NSTEP=16). Grid 512 = 8b x 16qt x 4quarters.
// R18-verified skeleton + T5 s_setprio around MFMA clusters (runtime hint
// only — no memory-ordering or codegen-structure change).
// ---------------------------------------------------------------------------
#define KVB 32
#define NSTEP 16

__global__ __launch_bounds__(256, 2) void attn(
    const short* __restrict__ Qb, const short* __restrict__ Kb,
    const short* __restrict__ Vt, short* __restrict__ Aq, float* __restrict__ lp)
{
    __shared__ short kbuf[2][KVB * C_];      // 16 KB (swizzled rows of 256B)
    __shared__ short vbuf[2][C_ * KVB];      // 16 KB (linear rows of 64B)
    __shared__ short pbuf[4][32 * 40];       // 10 KB per-wave P tile (32 rows)

    const int b       = blockIdx.x & 7;
    const int qt      = (blockIdx.x >> 3) & 15;
    const int quarter = blockIdx.x >> 7;
    const int q0      = qt * 128;
    const int tid = threadIdx.x, lane = tid & 63, w = tid >> 6;
    const int lr = lane & 15, lg = lane >> 4;
    const size_t LC = (size_t)L_ * C_;

    const char* KB = (const char*)(Kb + (size_t)b * LC);
    const char* VB = (const char*)(Vt + (size_t)b * LC);
    const int t0 = quarter * 16;             // first 32-wide kv tile

    // staging offsets: 2 K issues + 2 V issues per thread per tile
    int ksrc[2], vsrc[2], dsto[2];
#pragma unroll
    for (int i2 = 0; i2 < 2; ++i2) {
        const int p = w * 1024 + i2 * 4096 + lane * 16;   // linear byte in 8KB tile
        dsto[i2] = w * 1024 + i2 * 4096;                  // wave-uniform dest base
        const int krow = p >> 8, kcol = p & 255;
        ksrc[i2] = krow * 256 + (kcol ^ ((krow & 7) << 4));
        vsrc[i2] = (p >> 6) * (L_ * 2) + (p & 63);
    }
    char* kls = (char*)&kbuf[0][0];
    char* vls = (char*)&vbuf[0][0];

#define STAGE(PH, TILE) do {                                                   \
    const char* kg_ = KB + (size_t)(TILE) * 8192;                              \
    const char* vg_ = VB + (size_t)(TILE) * 64;                                \
    char* kd_ = kls + (PH) * 8192;                                             \
    char* vd_ = vls + (PH) * 8192;                                             \
    _Pragma("unroll")                                                          \
    for (int i2_ = 0; i2_ < 2; ++i2_) {                                        \
        gload16(kg_ + ksrc[i2_], kd_ + dsto[i2_]);                             \
        gload16(vg_ + vsrc[i2_], vd_ + dsto[i2_]);                             \
    } } while (0)

    // Q fragments: wave w owns rows q0 + w*32 + rg*16 + lr
    s8v qf[2][4];
#pragma unroll
    for (int rg = 0; rg < 2; ++rg)
#pragma unroll
        for (int kk = 0; kk < 4; ++kk)
            qf[rg][kk] = *(const s8v*)(Qb + (size_t)b * LC
                          + (size_t)(q0 + w * 32 + rg * 16 + lr) * C_ + kk * 32 + lg * 8);

    f4v of[2][8];
    float lsum[2][4];
#pragma unroll
    for (int rg = 0; rg < 2; ++rg) {
#pragma unroll
        for (int t = 0; t < 8; ++t) of[rg][t] = (f4v){0.f, 0.f, 0.f, 0.f};
#pragma unroll
        for (int r = 0; r < 4; ++r) lsum[rg][r] = 0.f;
    }

    short* myp = &pbuf[w][0];

    STAGE(0, t0);
    WAIT_VM0;
    __builtin_amdgcn_s_barrier();

#define STEP(PH, J) do {                                                       \
    if ((J) + 1 < NSTEP) STAGE((PH) ^ 1, t0 + (J) + 1);                        \
    const char* kl_ = kls + (PH) * 8192;                                       \
    const char* vl_ = vls + (PH) * 8192;                                       \
    f4v sc[2][2];                                                              \
    sc[0][0] = sc[0][1] = sc[1][0] = sc[1][1] = (f4v){0.f, 0.f, 0.f, 0.f};     \
    const int sw_ = (lr & 7) << 4;                                             \
    __builtin_amdgcn_s_setprio(1);                                             \
    _Pragma("unroll")                                                          \
    for (int st = 0; st < 2; ++st) {                                           \
        _Pragma("unroll")                                                      \
        for (int kk = 0; kk < 4; ++kk) {                                       \
            s8v kf = *(const s8v*)(kl_ + (st * 16 + lr) * 256                  \
                                   + ((kk * 64 + lg * 16) ^ sw_));             \
            sc[0][st] = __builtin_amdgcn_mfma_f32_16x16x32_bf16(qf[0][kk], kf, sc[0][st], 0, 0, 0); \
            sc[1][st] = __builtin_amdgcn_mfma_f32_16x16x32_bf16(qf[1][kk], kf, sc[1][st], 0, 0, 0); \
        }                                                                      \
    }                                                                          \
    __builtin_amdgcn_s_setprio(0);                                             \
    _Pragma("unroll")                                                          \
    for (int rg = 0; rg < 2; ++rg)                                             \
    _Pragma("unroll")                                                          \
    for (int r = 0; r < 4; ++r) {                                              \
        float p0_ = __builtin_amdgcn_exp2f(sc[rg][0][r] - ESHIFT);             \
        float p1_ = __builtin_amdgcn_exp2f(sc[rg][1][r] - ESHIFT);             \
        lsum[rg][r] += p0_ + p1_;                                              \
        const unsigned pk_ = cvt_pk_bf16(p0_, p1_);                            \
        const int prow_ = (rg * 16 + 4 * lg + r) * 40;                         \
        myp[prow_ + lr]      = (short)(pk_ & 0xffff);                          \
        myp[prow_ + 16 + lr] = (short)(pk_ >> 16);                             \
    }                                                                          \
    s8v pf0 = *(const s8v*)(myp + lr * 40 + lg * 8);                           \
    s8v pf1 = *(const s8v*)(myp + (16 + lr) * 40 + lg * 8);                    \
    __builtin_amdgcn_s_setprio(1);                                             \
    _Pragma("unroll")                                                          \
    for (int t = 0; t < 8; ++t) {                                              \
        s8v vf = *(const s8v*)(vl_ + (t * 16 + lr) * 64 + lg * 16);            \
        of[0][t] = __builtin_amdgcn_mfma_f32_16x16x32_bf16(pf0, vf, of[0][t], 0, 0, 0); \
        of[1][t] = __builtin_amdgcn_mfma_f32_16x16x32_bf16(pf1, vf, of[1][t], 0, 0, 0); \
    }                                                                          \
    __builtin_amdgcn_s_setprio(0);                                             \
    WAIT_VM0;                                                                  \
    __builtin_amdgcn_s_barrier();                                              \
    } while (0)

#pragma unroll 1
    for (int j = 0; j < NSTEP; j += 2) {
        STEP(0, j);
        STEP(1, j + 1);
    }

    // reduce l across the 16 k-col lanes
#pragma unroll
    for (int rg = 0; rg < 2; ++rg)
#pragma unroll
    for (int r = 0; r < 4; ++r) {
        float v = lsum[rg][r];
        v += __shfl_xor(v, 1);
        v += __shfl_xor(v, 2);
        v += __shfl_xor(v, 4);
        v += __shfl_xor(v, 8);
        lsum[rg][r] = v;
    }

    // direct write (no merge): bf16 A-partials + fp32 l-partials
    short* Abase = Aq + (size_t)quarter * NE + (size_t)b * LC;
    float* lbase = lp + (size_t)(quarter * B_ + b) * L_;
#pragma unroll
    for (int rg = 0; rg < 2; ++rg)
#pragma unroll
    for (int r = 0; r < 4; ++r) {
        const int row = q0 + w * 32 + rg * 16 + 4 * lg + r;
#pragma unroll
        for (int t = 0; t < 8; ++t)
            Abase[(size_t)row * C_ + t * 16 + lr] = f2bf(of[rg][t][r]);
        if (lr == 0) lbase[row] = lsum[rg][r];
    }
#undef STEP
#undef STAGE
}

// ---------------------------------------------------------------------------
// Kernel C: R = relu(sum_q Aq)/(sum_q l); out = x + Wo R^T + bo
// grid 512 = b(8) x 64 l-tiles of 32 rows; waves = rowhalf x nt-half
// ---------------------------------------------------------------------------
__global__ __launch_bounds__(256) void out_proj(
    const short* __restrict__ Aq, const float* __restrict__ lp,
    const short* __restrict__ Wb, const float* __restrict__ bo,
    const float* __restrict__ x, float* __restrict__ out)
{
    const int b  = blockIdx.x >> 6;
    const int l0 = (blockIdx.x & 63) * 32;
    const int tid = threadIdx.x, lane = tid & 63, w = tid >> 6;
    const int lr = lane & 15, lg = lane >> 4;
    const int rh = w >> 1, nh = w & 1;
    const size_t LC = (size_t)L_ * C_;
    const int row = l0 + rh * 16 + lr;

    const short* A0 = Aq + ((size_t)b * L_ + row) * C_;
    float lt = 0.f;
#pragma unroll
    for (int q = 0; q < 4; ++q) lt += lp[(size_t)(q * B_ + b) * L_ + row];
    const float linv = 1.0f / lt;

    s8v af[4];
#pragma unroll
    for (int kk = 0; kk < 4; ++kk) {
        s8v a0 = *(const s8v*)(A0 + 0 * (size_t)NE + kk * 32 + lg * 8);
        s8v a1 = *(const s8v*)(A0 + 1 * (size_t)NE + kk * 32 + lg * 8);
        s8v a2 = *(const s8v*)(A0 + 2 * (size_t)NE + kk * 32 + lg * 8);
        s8v a3 = *(const s8v*)(A0 + 3 * (size_t)NE + kk * 32 + lg * 8);
        union { s8v s; unsigned u[4]; } uf;
#pragma unroll
        for (int j2 = 0; j2 < 4; ++j2) {
            float v0 = (bf2f(a0[2*j2])   + bf2f(a1[2*j2]))   + (bf2f(a2[2*j2])   + bf2f(a3[2*j2]));
            float v1 = (bf2f(a0[2*j2+1]) + bf2f(a1[2*j2+1])) + (bf2f(a2[2*j2+1]) + bf2f(a3[2*j2+1]));
            uf.u[j2] = cvt_pk_bf16(fmaxf(v0, 0.f) * linv, fmaxf(v1, 0.f) * linv);
        }
        af[kk] = uf.s;
    }

    const short* Wo_b = Wb + 3 * 16384;
#pragma unroll
    for (int i = 0; i < 4; ++i) {
        const int nt = nh * 4 + i;
        f4v acc = {0.f, 0.f, 0.f, 0.f};
#pragma unroll
        for (int kk = 0; kk < 4; ++kk) {
            s8v wfr = *(const s8v*)(Wo_b + (size_t)(nt * 16 + lr) * C_ + kk * 32 + lg * 8);
            acc = __builtin_amdgcn_mfma_f32_16x16x32_bf16(af[kk], wfr, acc, 0, 0, 0);
        }
        const int o = nt * 16 + lr;
        const float bias = bo[o];
        const size_t base = (size_t)b * LC + (size_t)o * L_ + l0 + rh * 16 + 4 * lg;
        f4v xv = *(const f4v*)(x + base);
        f4v ov;
#pragma unroll
        for (int r = 0; r < 4; ++r) ov[r] = acc[r] + xv[r] + bias;
        *(f4v*)(out + base) = ov;
    }
}

extern "C" void kernel_launch(void* const* d_in, const int* in_sizes, int n_in,
                              void* d_out, int out_size, void* d_ws, size_t ws_size,
                              hipStream_t stream) {
    const float* x  = (const float*)d_in[0];
    const float* Wq = (const float*)d_in[1];
    const float* bq = (const float*)d_in[2];
    const float* Wk = (const float*)d_in[3];
    const float* bk = (const float*)d_in[4];
    const float* Wv = (const float*)d_in[5];
    const float* bv = (const float*)d_in[6];
    const float* Wo = (const float*)d_in[7];
    const float* bo = (const float*)d_in[8];
    float* out = (float*)d_out;

    short* Qb  = (short*)d_ws;                 // NE bf16
    short* Kb  = Qb + NE;                      // NE bf16
    short* Vt  = Kb + NE;                      // NE bf16 (transposed)
    short* Wb  = Vt + NE;                      // 4*16384 bf16 weights
    float* bqs = (float*)(Wb + 4 * 16384);     // 128 fp32
    short* Aq  = (short*)(bqs + 128);          // 4*NE bf16 partial A
    float* lp  = (float*)(Aq + 4 * (size_t)NE);// 4*B*L fp32 partial l

    prep    <<<16,   256, 0, stream>>>(Wq, Wk, Wv, Wo, bq, Wb, bqs);
    qkv_proj<<<1024, 256, 0, stream>>>(x, Wb, bqs, bk, bv, Qb, Kb, Vt);
    attn    <<<512,  256, 0, stream>>>(Qb, Kb, Vt, Aq, lp);
    out_proj<<<512,  256, 0, stream>>>(Aq, lp, Wb, bo, x, out);
}

// Round 20
// 65.990 us; speedup vs baseline: 1.0127x; 1.0127x over previous
//
#include <hip/hip_runtime.h>

#define B_ 8
#define C_ 128
#define L_ 2048
#define NE (B_ * L_ * C_)

typedef __attribute__((ext_vector_type(8))) short s8v;
typedef __attribute__((ext_vector_type(4))) short s4v;
typedef __attribute__((ext_vector_type(4))) float f4v;
typedef __attribute__((ext_vector_type(8))) float f8v;

// 1/sqrt(128) * log2(e)  (folded into Wq/bq so attn uses exp2 directly)
#define QSCALE 0.1275174106f
// 8 * log2(e)
#define ESHIFT 11.5415603272f

static __device__ inline short f2bf(float f) {
    union { float f; unsigned u; } v; v.f = f;
    unsigned r = v.u + 0x7FFFu + ((v.u >> 16) & 1u);
    return (short)(r >> 16);
}
static __device__ inline float bf2f(short s) {
    union { unsigned u; float f; } v; v.u = ((unsigned)(unsigned short)s) << 16;
    return v.f;
}
static __device__ inline unsigned cvt_pk_bf16(float lo, float hi) {
    unsigned r;
    asm("v_cvt_pk_bf16_f32 %0, %1, %2" : "=v"(r) : "v"(lo), "v"(hi));
    return r;
}
static __device__ inline void gload16(const void* g, void* l) {
    __builtin_amdgcn_global_load_lds(
        (const __attribute__((address_space(1))) unsigned int*)g,
        (__attribute__((address_space(3))) unsigned int*)l, 16, 0, 0);
}

#define WAIT_VM0 asm volatile("s_waitcnt vmcnt(0)" ::: "memory")

// ---------------------------------------------------------------------------
// prep: bf16 weights (Wq pre-scaled by QSCALE), scaled bq. grid 16x256.
// ---------------------------------------------------------------------------
__global__ __launch_bounds__(256) void prep(
    const float* __restrict__ Wq, const float* __restrict__ Wk,
    const float* __restrict__ Wv, const float* __restrict__ Wo,
    const float* __restrict__ bq, short* __restrict__ Wb, float* __restrict__ bqs)
{
    const int i = (blockIdx.x * 256 + threadIdx.x) * 4;
    const float* src[4] = { Wq, Wk, Wv, Wo };
#pragma unroll
    for (int m = 0; m < 4; ++m) {
        f4v v = *(const f4v*)(src[m] + i);
        const float mul = (m == 0) ? QSCALE : 1.f;
        union { s4v s; unsigned u[2]; } o;
        o.u[0] = cvt_pk_bf16(v[0] * mul, v[1] * mul);
        o.u[1] = cvt_pk_bf16(v[2] * mul, v[3] * mul);
        *(s4v*)(Wb + m * 16384 + i) = o.s;
    }
    if (blockIdx.x == 0 && threadIdx.x < C_) bqs[threadIdx.x] = bq[threadIdx.x] * QSCALE;
}

// ---------------------------------------------------------------------------
// Kernel A: h = relu(x); Q,K -> [B][L][C] bf16 ; V -> [B][C][L] bf16
// grid 1024 = b(8) x 128 l-tiles of 16 rows; waves own 6 (mat,nt) tiles each
// ---------------------------------------------------------------------------
__global__ __launch_bounds__(256) void qkv_proj(
    const float* __restrict__ x, const short* __restrict__ Wb,
    const float* __restrict__ bqs, const float* __restrict__ bk,
    const float* __restrict__ bv,
    short* __restrict__ Qb, short* __restrict__ Kb, short* __restrict__ Vt)
{
    __shared__ short ht[16][136];
    const int b  = blockIdx.x >> 7;
    const int l0 = (blockIdx.x & 127) * 16;
    const int tid = threadIdx.x;

    {
        const int c = tid >> 1, lh = (tid & 1) * 8;
        f8v v = *(const f8v*)(x + ((size_t)b * C_ + c) * L_ + l0 + lh);
#pragma unroll
        for (int j = 0; j < 8; ++j) ht[lh + j][c] = f2bf(fmaxf(v[j], 0.f));
    }
    __syncthreads();

    const int lane = tid & 63, w = tid >> 6;
    const int lr = lane & 15, lg = lane >> 4;

    s8v hf[4];
#pragma unroll
    for (int kk = 0; kk < 4; ++kk)
        hf[kk] = *(const s8v*)&ht[lr][kk * 32 + lg * 8];

#pragma unroll
    for (int i = 0; i < 6; ++i) {
        const int idx = w * 6 + i;
        const int mat = idx >> 3, nt = idx & 7;
        const short* W = Wb + mat * 16384;
        f4v acc = {0.f, 0.f, 0.f, 0.f};
#pragma unroll
        for (int kk = 0; kk < 4; ++kk) {
            s8v wfr = *(const s8v*)(W + (size_t)(nt * 16 + lr) * C_ + kk * 32 + lg * 8);
            acc = __builtin_amdgcn_mfma_f32_16x16x32_bf16(hf[kk], wfr, acc, 0, 0, 0);
        }
        const int o = nt * 16 + lr;
        const float bsc = (mat == 0 ? bqs : (mat == 1 ? bk : bv))[o];
        if (mat == 0) {
#pragma unroll
            for (int r = 0; r < 4; ++r)
                Qb[((size_t)b * L_ + l0 + 4 * lg + r) * C_ + o] = f2bf(acc[r] + bsc);
        } else if (mat == 1) {
#pragma unroll
            for (int r = 0; r < 4; ++r)
                Kb[((size_t)b * L_ + l0 + 4 * lg + r) * C_ + o] = f2bf(acc[r] + bsc);
        } else {
            union { s4v s; unsigned u[2]; } pk;
            pk.u[0] = cvt_pk_bf16(acc[0] + bsc, acc[1] + bsc);
            pk.u[1] = cvt_pk_bf16(acc[2] + bsc, acc[3] + bsc);
            *(s4v*)(Vt + ((size_t)b * C_ + o) * L_ + l0 + 4 * lg) = pk.s;
        }
    }
}

// ---------------------------------------------------------------------------
// Kernel B: flash attention, fixed-shift exp2 softmax, 4-way split-K.
// QBLK=128: each wave owns 32 q-rows (2 rowgroups), all 4 waves share each
// KV tile (KVB=32, NSTEP=16). Grid 512 = 8b x 16qt x 4quarters.
// LDS 42.2 KB -> 3 blocks/CU. R12's verified skeleton, 2x MFMA per step.
// ---------------------------------------------------------------------------
#define KVB 32
#define NSTEP 16

__global__ __launch_bounds__(256, 2) void attn(
    const short* __restrict__ Qb, const short* __restrict__ Kb,
    const short* __restrict__ Vt, short* __restrict__ Aq, float* __restrict__ lp)
{
    __shared__ short kbuf[2][KVB * C_];      // 16 KB (swizzled rows of 256B)
    __shared__ short vbuf[2][C_ * KVB];      // 16 KB (linear rows of 64B)
    __shared__ short pbuf[4][32 * 40];       // 10 KB per-wave P tile (32 rows)

    const int b       = blockIdx.x & 7;
    const int qt      = (blockIdx.x >> 3) & 15;
    const int quarter = blockIdx.x >> 7;
    const int q0      = qt * 128;
    const int tid = threadIdx.x, lane = tid & 63, w = tid >> 6;
    const int lr = lane & 15, lg = lane >> 4;
    const size_t LC = (size_t)L_ * C_;

    const char* KB = (const char*)(Kb + (size_t)b * LC);
    const char* VB = (const char*)(Vt + (size_t)b * LC);
    const int t0 = quarter * 16;             // first 32-wide kv tile

    // staging offsets: 2 K issues + 2 V issues per thread per tile
    int ksrc[2], vsrc[2], dsto[2];
#pragma unroll
    for (int i2 = 0; i2 < 2; ++i2) {
        const int p = w * 1024 + i2 * 4096 + lane * 16;   // linear byte in 8KB tile
        dsto[i2] = w * 1024 + i2 * 4096;                  // wave-uniform dest base
        const int krow = p >> 8, kcol = p & 255;
        ksrc[i2] = krow * 256 + (kcol ^ ((krow & 7) << 4));
        vsrc[i2] = (p >> 6) * (L_ * 2) + (p & 63);
    }
    char* kls = (char*)&kbuf[0][0];
    char* vls = (char*)&vbuf[0][0];

#define STAGE(PH, TILE) do {                                                   \
    const char* kg_ = KB + (size_t)(TILE) * 8192;                              \
    const char* vg_ = VB + (size_t)(TILE) * 64;                                \
    char* kd_ = kls + (PH) * 8192;                                             \
    char* vd_ = vls + (PH) * 8192;                                             \
    _Pragma("unroll")                                                          \
    for (int i2_ = 0; i2_ < 2; ++i2_) {                                        \
        gload16(kg_ + ksrc[i2_], kd_ + dsto[i2_]);                             \
        gload16(vg_ + vsrc[i2_], vd_ + dsto[i2_]);                             \
    } } while (0)

    // Q fragments: wave w owns rows q0 + w*32 + rg*16 + lr
    s8v qf[2][4];
#pragma unroll
    for (int rg = 0; rg < 2; ++rg)
#pragma unroll
        for (int kk = 0; kk < 4; ++kk)
            qf[rg][kk] = *(const s8v*)(Qb + (size_t)b * LC
                          + (size_t)(q0 + w * 32 + rg * 16 + lr) * C_ + kk * 32 + lg * 8);

    f4v of[2][8];
    float lsum[2][4];
#pragma unroll
    for (int rg = 0; rg < 2; ++rg) {
#pragma unroll
        for (int t = 0; t < 8; ++t) of[rg][t] = (f4v){0.f, 0.f, 0.f, 0.f};
#pragma unroll
        for (int r = 0; r < 4; ++r) lsum[rg][r] = 0.f;
    }

    short* myp = &pbuf[w][0];

    STAGE(0, t0);
    WAIT_VM0;
    __builtin_amdgcn_s_barrier();

#define STEP(PH, J) do {                                                       \
    if ((J) + 1 < NSTEP) STAGE((PH) ^ 1, t0 + (J) + 1);                        \
    const char* kl_ = kls + (PH) * 8192;                                       \
    const char* vl_ = vls + (PH) * 8192;                                       \
    f4v sc[2][2];                                                              \
    sc[0][0] = sc[0][1] = sc[1][0] = sc[1][1] = (f4v){0.f, 0.f, 0.f, 0.f};     \
    const int sw_ = (lr & 7) << 4;                                             \
    _Pragma("unroll")                                                          \
    for (int st = 0; st < 2; ++st) {                                           \
        _Pragma("unroll")                                                      \
        for (int kk = 0; kk < 4; ++kk) {                                       \
            s8v kf = *(const s8v*)(kl_ + (st * 16 + lr) * 256                  \
                                   + ((kk * 64 + lg * 16) ^ sw_));             \
            sc[0][st] = __builtin_amdgcn_mfma_f32_16x16x32_bf16(qf[0][kk], kf, sc[0][st], 0, 0, 0); \
            sc[1][st] = __builtin_amdgcn_mfma_f32_16x16x32_bf16(qf[1][kk], kf, sc[1][st], 0, 0, 0); \
        }                                                                      \
    }                                                                          \
    _Pragma("unroll")                                                          \
    for (int rg = 0; rg < 2; ++rg)                                             \
    _Pragma("unroll")                                                          \
    for (int r = 0; r < 4; ++r) {                                              \
        float p0_ = __builtin_amdgcn_exp2f(sc[rg][0][r] - ESHIFT);             \
        float p1_ = __builtin_amdgcn_exp2f(sc[rg][1][r] - ESHIFT);             \
        lsum[rg][r] += p0_ + p1_;                                              \
        const unsigned pk_ = cvt_pk_bf16(p0_, p1_);                            \
        const int prow_ = (rg * 16 + 4 * lg + r) * 40;                         \
        myp[prow_ + lr]      = (short)(pk_ & 0xffff);                          \
        myp[prow_ + 16 + lr] = (short)(pk_ >> 16);                             \
    }                                                                          \
    s8v pf0 = *(const s8v*)(myp + lr * 40 + lg * 8);                           \
    s8v pf1 = *(const s8v*)(myp + (16 + lr) * 40 + lg * 8);                    \
    _Pragma("unroll")                                                          \
    for (int t = 0; t < 8; ++t) {                                              \
        s8v vf = *(const s8v*)(vl_ + (t * 16 + lr) * 64 + lg * 16);            \
        of[0][t] = __builtin_amdgcn_mfma_f32_16x16x32_bf16(pf0, vf, of[0][t], 0, 0, 0); \
        of[1][t] = __builtin_amdgcn_mfma_f32_16x16x32_bf16(pf1, vf, of[1][t], 0, 0, 0); \
    }                                                                          \
    WAIT_VM0;                                                                  \
    __builtin_amdgcn_s_barrier();                                              \
    } while (0)

#pragma unroll 1
    for (int j = 0; j < NSTEP; j += 2) {
        STEP(0, j);
        STEP(1, j + 1);
    }

    // reduce l across the 16 k-col lanes
#pragma unroll
    for (int rg = 0; rg < 2; ++rg)
#pragma unroll
    for (int r = 0; r < 4; ++r) {
        float v = lsum[rg][r];
        v += __shfl_xor(v, 1);
        v += __shfl_xor(v, 2);
        v += __shfl_xor(v, 4);
        v += __shfl_xor(v, 8);
        lsum[rg][r] = v;
    }

    // direct write (no merge): bf16 A-partials + fp32 l-partials
    short* Abase = Aq + (size_t)quarter * NE + (size_t)b * LC;
    float* lbase = lp + (size_t)(quarter * B_ + b) * L_;
#pragma unroll
    for (int rg = 0; rg < 2; ++rg)
#pragma unroll
    for (int r = 0; r < 4; ++r) {
        const int row = q0 + w * 32 + rg * 16 + 4 * lg + r;
#pragma unroll
        for (int t = 0; t < 8; ++t)
            Abase[(size_t)row * C_ + t * 16 + lr] = f2bf(of[rg][t][r]);
        if (lr == 0) lbase[row] = lsum[rg][r];
    }
#undef STEP
#undef STAGE
}

// ---------------------------------------------------------------------------
// Kernel C: R = relu(sum_q Aq)/(sum_q l); out = x + Wo R^T + bo
// grid 512 = b(8) x 64 l-tiles of 32 rows; waves = rowhalf x nt-half
// ---------------------------------------------------------------------------
__global__ __launch_bounds__(256) void out_proj(
    const short* __restrict__ Aq, const float* __restrict__ lp,
    const short* __restrict__ Wb, const float* __restrict__ bo,
    const float* __restrict__ x, float* __restrict__ out)
{
    const int b  = blockIdx.x >> 6;
    const int l0 = (blockIdx.x & 63) * 32;
    const int tid = threadIdx.x, lane = tid & 63, w = tid >> 6;
    const int lr = lane & 15, lg = lane >> 4;
    const int rh = w >> 1, nh = w & 1;
    const size_t LC = (size_t)L_ * C_;
    const int row = l0 + rh * 16 + lr;

    const short* A0 = Aq + ((size_t)b * L_ + row) * C_;
    float lt = 0.f;
#pragma unroll
    for (int q = 0; q < 4; ++q) lt += lp[(size_t)(q * B_ + b) * L_ + row];
    const float linv = 1.0f / lt;

    s8v af[4];
#pragma unroll
    for (int kk = 0; kk < 4; ++kk) {
        s8v a0 = *(const s8v*)(A0 + 0 * (size_t)NE + kk * 32 + lg * 8);
        s8v a1 = *(const s8v*)(A0 + 1 * (size_t)NE + kk * 32 + lg * 8);
        s8v a2 = *(const s8v*)(A0 + 2 * (size_t)NE + kk * 32 + lg * 8);
        s8v a3 = *(const s8v*)(A0 + 3 * (size_t)NE + kk * 32 + lg * 8);
        union { s8v s; unsigned u[4]; } uf;
#pragma unroll
        for (int j2 = 0; j2 < 4; ++j2) {
            float v0 = (bf2f(a0[2*j2])   + bf2f(a1[2*j2]))   + (bf2f(a2[2*j2])   + bf2f(a3[2*j2]));
            float v1 = (bf2f(a0[2*j2+1]) + bf2f(a1[2*j2+1])) + (bf2f(a2[2*j2+1]) + bf2f(a3[2*j2+1]));
            uf.u[j2] = cvt_pk_bf16(fmaxf(v0, 0.f) * linv, fmaxf(v1, 0.f) * linv);
        }
        af[kk] = uf.s;
    }

    const short* Wo_b = Wb + 3 * 16384;
#pragma unroll
    for (int i = 0; i < 4; ++i) {
        const int nt = nh * 4 + i;
        f4v acc = {0.f, 0.f, 0.f, 0.f};
#pragma unroll
        for (int kk = 0; kk < 4; ++kk) {
            s8v wfr = *(const s8v*)(Wo_b + (size_t)(nt * 16 + lr) * C_ + kk * 32 + lg * 8);
            acc = __builtin_amdgcn_mfma_f32_16x16x32_bf16(af[kk], wfr, acc, 0, 0, 0);
        }
        const int o = nt * 16 + lr;
        const float bias = bo[o];
        const size_t base = (size_t)b * LC + (size_t)o * L_ + l0 + rh * 16 + 4 * lg;
        f4v xv = *(const f4v*)(x + base);
        f4v ov;
#pragma unroll
        for (int r = 0; r < 4; ++r) ov[r] = acc[r] + xv[r] + bias;
        *(f4v*)(out + base) = ov;
    }
}

extern "C" void kernel_launch(void* const* d_in, const int* in_sizes, int n_in,
                              void* d_out, int out_size, void* d_ws, size_t ws_size,
                              hipStream_t stream) {
    const float* x  = (const float*)d_in[0];
    const float* Wq = (const float*)d_in[1];
    const float* bq = (const float*)d_in[2];
    const float* Wk = (const float*)d_in[3];
    const float* bk = (const float*)d_in[4];
    const float* Wv = (const float*)d_in[5];
    const float* bv = (const float*)d_in[6];
    const float* Wo = (const float*)d_in[7];
    const float* bo = (const float*)d_in[8];
    float* out = (float*)d_out;

    short* Qb  = (short*)d_ws;                 // NE bf16
    short* Kb  = Qb + NE;                      // NE bf16
    short* Vt  = Kb + NE;                      // NE bf16 (transposed)
    short* Wb  = Vt + NE;                      // 4*16384 bf16 weights
    float* bqs = (float*)(Wb + 4 * 16384);     // 128 fp32
    short* Aq  = (short*)(bqs + 128);          // 4*NE bf16 partial A
    float* lp  = (float*)(Aq + 4 * (size_t)NE);// 4*B*L fp32 partial l

    prep    <<<16,   256, 0, stream>>>(Wq, Wk, Wv, Wo, bq, Wb, bqs);
    qkv_proj<<<1024, 256, 0, stream>>>(x, Wb, bqs, bk, bv, Qb, Kb, Vt);
    attn    <<<512,  256, 0, stream>>>(Qb, Kb, Vt, Aq, lp);
    out_proj<<<512,  256, 0, stream>>>(Aq, lp, Wb, bo, x, out);
}